// Round 5
// baseline (716.750 us; speedup 1.0000x reference)
//
#include <hip/hip_runtime.h>
#include <hip/hip_bf16.h>
#include <cstdint>

// TGAT fused pipeline for MI355X — round 4: atomic-free aggregation.
// Stages:
//   k1: h1pre = x @ Wlin + blin                        [N,32]
//   k2: node encoders + gated combine + Q/K/V/skip     [N,32] x4
//   sort: counting sort of edges by dst (hist -> 3-kernel scan -> scatter)
//         producing CSR (rowptr) + per-edge (src, rel_time_f16)
//   k3_fused: one wave per dst node — MFMA edge features, attention,
//         exact register aggregation (no atomics), fused skip+Wout+log_softmax
//
// Workspace (~71 MB): qb|kb|vb|skipb (4x12.8MB) | h1pre<->src_s (12.8MB) |
//                     rel_h f16 (6.4MB) | rowptr | cnt/cursor | bsums

#define FIN 172
#define INV_SQRT_C 0.25f
#define SCAN_ELEMS 1024

typedef _Float16 f16x8 __attribute__((ext_vector_type(8)));
typedef float f32x4 __attribute__((ext_vector_type(4)));

// ---------------------------------------------------------------------------
// k1: h1pre = x @ Wlin + blin.  Block = 256 threads = 8 rows x 32 out-cols.
// ---------------------------------------------------------------------------
__global__ __launch_bounds__(256) void k1_lin(
    const float* __restrict__ x, const float* __restrict__ Wlin,
    const float* __restrict__ blin, float* __restrict__ h1pre, int n)
{
    __shared__ __align__(16) float WlT[32][174];   // [out][k], padded
    __shared__ __align__(16) float xs[8][FIN];
    const int t = threadIdx.x;

    for (int i = t; i < FIN * 32; i += 256) {
        int kk = i >> 5, o = i & 31;               // Wlin row-major [k][o]
        WlT[o][kk] = Wlin[i];
    }
    const int row0 = blockIdx.x * 8;
    for (int i = t; i < 8 * FIN; i += 256) {
        int rr = i / FIN, kk = i - rr * FIN;
        int gr = row0 + rr;
        xs[rr][kk] = (gr < n) ? x[(size_t)gr * FIN + kk] : 0.f;
    }
    __syncthreads();

    const int o = t & 31, r = t >> 5;
    float acc = blin[o];
    const float2* wp = reinterpret_cast<const float2*>(&WlT[o][0]);
    const float2* xp = reinterpret_cast<const float2*>(&xs[r][0]);
    #pragma unroll 4
    for (int kk = 0; kk < FIN / 2; ++kk) {
        float2 wv = wp[kk], xv = xp[kk];
        acc = fmaf(xv.x, wv.x, acc);
        acc = fmaf(xv.y, wv.y, acc);
    }
    const int gr = row0 + r;
    if (gr < n) h1pre[(size_t)gr * 32 + o] = acc;
}

// ---------------------------------------------------------------------------
// Small matvec helper: out[o] = B[o] + sum_k v[k] * W[k*O + o]. W/B in LDS.
// ---------------------------------------------------------------------------
template <int K, int O>
__device__ __forceinline__ void matvecKO(const float* __restrict__ v,
                                         const float* __restrict__ W,
                                         const float* __restrict__ B,
                                         float* __restrict__ out)
{
    #pragma unroll
    for (int o4 = 0; o4 < O / 4; ++o4) {
        float a0 = B[o4 * 4 + 0], a1 = B[o4 * 4 + 1];
        float a2 = B[o4 * 4 + 2], a3 = B[o4 * 4 + 3];
        #pragma unroll
        for (int k = 0; k < K; ++k) {
            float4 wv = *reinterpret_cast<const float4*>(&W[k * O + o4 * 4]);
            float hv = v[k];
            a0 = fmaf(hv, wv.x, a0);
            a1 = fmaf(hv, wv.y, a1);
            a2 = fmaf(hv, wv.z, a2);
            a3 = fmaf(hv, wv.w, a3);
        }
        out[o4 * 4 + 0] = a0; out[o4 * 4 + 1] = a1;
        out[o4 * 4 + 2] = a2; out[o4 * 4 + 3] = a3;
    }
}

__device__ __forceinline__ void store32(float* __restrict__ dst,
                                        const float* __restrict__ v)
{
    float4* d4 = reinterpret_cast<float4*>(dst);
    #pragma unroll
    for (int i = 0; i < 8; ++i)
        d4[i] = make_float4(v[4 * i], v[4 * i + 1], v[4 * i + 2], v[4 * i + 3]);
}

// ---------------------------------------------------------------------------
// k2: per-node encoder + combine + projections. One thread per node.
// ---------------------------------------------------------------------------
__global__ __launch_bounds__(256) void k2_enc(
    const float* __restrict__ h1pre,
    const float* __restrict__ node_interval, const float* __restrict__ node_degree,
    const float* __restrict__ Wtf, const float* __restrict__ btf,
    const float* __restrict__ Wd,  const float* __restrict__ bd,
    const float* __restrict__ Wenc, const float* __restrict__ benc,
    const float* __restrict__ Wx,  const float* __restrict__ bx,
    const float* __restrict__ Wcomb, const float* __restrict__ bcomb,
    const float* __restrict__ Wq,  const float* __restrict__ bq,
    const float* __restrict__ Wk,  const float* __restrict__ bk,
    const float* __restrict__ Wv,  const float* __restrict__ bv,
    const float* __restrict__ Wskip, const float* __restrict__ bskip,
    float* __restrict__ qb, float* __restrict__ kb, float* __restrict__ vb,
    float* __restrict__ skipb, int n)
{
    __shared__ __align__(16) float sWenc[64], sWx[256], sWcomb[1280];
    __shared__ __align__(16) float sWq[1024], sWk[1024], sWv[1024], sWs[1024];
    __shared__ float sWtf[8], sbtf[8], sWd[8], sbd[8], sbenc[8], sbx[8];
    __shared__ float sbcomb[32], sbq[32], sbk[32], sbv[32], sbs[32];

    const int t = threadIdx.x;
    if (t < 8) {
        sWtf[t] = Wtf[t]; sbtf[t] = btf[t];
        sWd[t]  = Wd[t];  sbd[t]  = bd[t];
        sbenc[t] = benc[t]; sbx[t] = bx[t];
    }
    if (t < 32) {
        sbcomb[t] = bcomb[t]; sbq[t] = bq[t]; sbk[t] = bk[t];
        sbv[t] = bv[t]; sbs[t] = bskip[t];
    }
    if (t < 64) sWenc[t] = Wenc[t];
    if (t < 256) sWx[t] = Wx[t];
    for (int i = t; i < 1280; i += 256) sWcomb[i] = Wcomb[i];
    for (int i = t; i < 1024; i += 256) {
        sWq[i] = Wq[i]; sWk[i] = Wk[i]; sWv[i] = Wv[i]; sWs[i] = Wskip[i];
    }
    __syncthreads();

    const int nid = blockIdx.x * 256 + t;
    if (nid >= n) return;

    float h1p[32];
    {
        const float2* hp = reinterpret_cast<const float2*>(h1pre + (size_t)nid * 32);
        #pragma unroll
        for (int i = 0; i < 16; ++i) {
            float2 v2 = hp[i];
            h1p[2 * i] = v2.x; h1p[2 * i + 1] = v2.y;
        }
    }
    const float ti = node_interval[nid], dg = node_degree[nid];
    float tf[8], de[8];
    #pragma unroll
    for (int j = 0; j < 8; ++j) {
        tf[j] = fmaf(ti, sWtf[j], sbtf[j]);
        de[j] = fmaf(dg, sWd[j], sbd[j]);
    }
    float xp[8];
    matvecKO<32, 8>(h1p, sWx, sbx, xp);
    #pragma unroll
    for (int o = 0; o < 8; ++o) xp[o] = tanhf(xp[o]);

    float ep0[8], ep1[8];
    matvecKO<8, 8>(tf, sWenc, sbenc, ep0);
    matvecKO<8, 8>(de, sWenc, sbenc, ep1);
    float sc0 = 0.f, sc1 = 0.f;
    #pragma unroll
    for (int o = 0; o < 8; ++o) {
        sc0 = fmaf(tanhf(ep0[o]), xp[o], sc0);
        sc1 = fmaf(tanhf(ep1[o]), xp[o], sc1);
    }
    const float mm = fmaxf(sc0, sc1);
    const float e0 = __expf(sc0 - mm), e1 = __expf(sc1 - mm);
    const float inv = 1.f / (e0 + e1);
    const float s0 = e0 * inv, s1 = e1 * inv;

    float v40[40];
    #pragma unroll
    for (int i = 0; i < 32; ++i) v40[i] = h1p[i];
    #pragma unroll
    for (int j = 0; j < 8; ++j) v40[32 + j] = fmaf(s0, tf[j], s1 * de[j]);
    float h1[32];
    matvecKO<40, 32>(v40, sWcomb, sbcomb, h1);

    float tmp[32];
    matvecKO<32, 32>(h1, sWq, sbq, tmp); store32(qb   + (size_t)nid * 32, tmp);
    matvecKO<32, 32>(h1, sWk, sbk, tmp); store32(kb   + (size_t)nid * 32, tmp);
    matvecKO<32, 32>(h1, sWv, sbv, tmp); store32(vb   + (size_t)nid * 32, tmp);
    matvecKO<32, 32>(h1, sWs, sbs, tmp); store32(skipb + (size_t)nid * 32, tmp);
}

// ---------------------------------------------------------------------------
// Counting sort by dst: hist -> scan (3 kernels) -> scatter.
// ---------------------------------------------------------------------------
__global__ __launch_bounds__(256) void k_hist(
    const int* __restrict__ ei, int* __restrict__ cnt, int numE)
{
    int e = blockIdx.x * 256 + threadIdx.x;
    const int stride = gridDim.x * 256;
    for (; e < numE; e += stride)
        atomicAdd(&cnt[ei[numE + e]], 1);
}

// scan1: per-block (1024-element chunk) sum -> bsums
__global__ __launch_bounds__(256) void k_scan1(
    const int* __restrict__ cnt, int* __restrict__ bsums, int n)
{
    __shared__ int red[256];
    const int base = blockIdx.x * SCAN_ELEMS;
    const int t = threadIdx.x;
    int s = 0;
    #pragma unroll
    for (int i = 0; i < 4; ++i) {
        int idx = base + t * 4 + i;
        if (idx < n) s += cnt[idx];
    }
    red[t] = s; __syncthreads();
    for (int off = 128; off > 0; off >>= 1) {
        if (t < off) red[t] += red[t + off];
        __syncthreads();
    }
    if (t == 0) bsums[blockIdx.x] = red[0];
}

// scan2: single block, exclusive scan of bsums (nb <= 1024)
__global__ __launch_bounds__(1024) void k_scan2(int* __restrict__ bsums, int nb)
{
    __shared__ int sh[1024];
    const int t = threadIdx.x;
    const int v = (t < nb) ? bsums[t] : 0;
    sh[t] = v; __syncthreads();
    for (int off = 1; off < 1024; off <<= 1) {
        int add = (t >= off) ? sh[t - off] : 0;
        __syncthreads();
        sh[t] += add;
        __syncthreads();
    }
    if (t < nb) bsums[t] = sh[t] - v;   // exclusive
}

// scan3: within-block exclusive scan + block offset -> rowptr & cursor(cnt)
__global__ __launch_bounds__(256) void k_scan3(
    int* __restrict__ cnt, const int* __restrict__ bsums,
    int* __restrict__ rowptr, int n, int total)
{
    __shared__ int tsum[256];
    const int base = blockIdx.x * SCAN_ELEMS;
    const int t = threadIdx.x;
    int loc[4]; int s = 0;
    #pragma unroll
    for (int i = 0; i < 4; ++i) {
        int idx = base + t * 4 + i;
        loc[i] = (idx < n) ? cnt[idx] : 0;
        s += loc[i];
    }
    tsum[t] = s; __syncthreads();
    const int v = s;
    for (int off = 1; off < 256; off <<= 1) {
        int add = (t >= off) ? tsum[t - off] : 0;
        __syncthreads();
        tsum[t] += add;
        __syncthreads();
    }
    int run = bsums[blockIdx.x] + (tsum[t] - v);
    #pragma unroll
    for (int i = 0; i < 4; ++i) {
        int idx = base + t * 4 + i;
        if (idx < n) { rowptr[idx] = run; cnt[idx] = run; run += loc[i]; }
    }
    if (blockIdx.x == 0 && t == 0) rowptr[n] = total;
}

__global__ __launch_bounds__(256) void k_scatter(
    const int* __restrict__ ei, const float* __restrict__ node_time,
    const float* __restrict__ edge_time, int* __restrict__ cursor,
    int* __restrict__ src_s, _Float16* __restrict__ rel_h, int numE)
{
    int e = blockIdx.x * 256 + threadIdx.x;
    const int stride = gridDim.x * 256;
    for (; e < numE; e += stride) {
        const int dst = ei[numE + e];
        const int src = ei[e];
        const int pos = atomicAdd(&cursor[dst], 1);
        src_s[pos] = src;
        rel_h[pos] = (_Float16)(node_time[src] - edge_time[e]);
    }
}

// ---------------------------------------------------------------------------
// k3_fused: one wave per dst node (grid-stride). Per 16-edge tile: MFMA edge
// features (two mfma_f32_16x16x32_f16), attention dot via in-group shfl_xor,
// exp(alpha) weights accumulated in registers (softmax shift-invariant, alpha
// is O(0.3)). After the segment: cross-group merge (xor16/32), normalize, add
// skip, @Wout + log_softmax, one 8B store per node. Zero atomics, zero LDS.
// ---------------------------------------------------------------------------
__global__ __launch_bounds__(256) void k3_fused(
    const int* __restrict__ rowptr, const int* __restrict__ src_s,
    const _Float16* __restrict__ rel_h,
    const float* __restrict__ qb, const float* __restrict__ kb,
    const float* __restrict__ vb, const float* __restrict__ skipb,
    const float* __restrict__ Wt, const float* __restrict__ bt,
    const float* __restrict__ We, const float* __restrict__ be,
    const float* __restrict__ Wout, const float* __restrict__ bout,
    float* __restrict__ out, int n)
{
    const int lane = threadIdx.x & 63;
    const int g = lane >> 4;          // k-group (MFMA) / partial-sum group
    const int m = lane & 15;          // A row (edge-in-tile) / channel within head

    // Per-thread constants, loaded once (grid-stride persistent waves).
    float wtr[8], btr[8];
    f16x8 B0, B1;
    #pragma unroll
    for (int i = 0; i < 8; ++i) {
        const int k = g * 8 + i;
        wtr[i] = Wt[k]; btr[i] = bt[k];
        B0[i] = (_Float16)We[k * 32 + m];
        B1[i] = (_Float16)We[k * 32 + 16 + m];
    }
    const float be0 = be[m], be1 = be[16 + m];
    const float w00 = Wout[m * 2],        w01 = Wout[m * 2 + 1];
    const float w10 = Wout[(16 + m) * 2], w11 = Wout[(16 + m) * 2 + 1];
    const float bo0 = bout[0], bo1 = bout[1];

    const int wid = blockIdx.x * (blockDim.x >> 6) + (threadIdx.x >> 6);
    const int nW  = gridDim.x * (blockDim.x >> 6);

    for (int d = wid; d < n; d += nW) {
        const int beg = rowptr[d], end = rowptr[d + 1];
        const size_t db = (size_t)d * 32;
        const float q0 = qb[db + m], q1 = qb[db + 16 + m];

        float o0 = 0.f, o1 = 0.f, s0 = 0.f, s1 = 0.f;   // per-group partials

        for (int t0 = beg; t0 < end; t0 += 16) {
            const int eA = t0 + m;                       // lane m owns edge t0+m
            const bool vA = eA < end;
            const int srcm  = vA ? src_s[eA] : 0;
            const float rel = vA ? (float)rel_h[eA] : 0.f;

            f16x8 A;                                     // ct[k], k = 8g+i
            #pragma unroll
            for (int i = 0; i < 8; ++i)
                A[i] = (_Float16)__cosf(fmaf(rel, wtr[i], btr[i]));

            f32x4 acc0 = {0.f, 0.f, 0.f, 0.f};
            f32x4 acc1 = {0.f, 0.f, 0.f, 0.f};
            acc0 = __builtin_amdgcn_mfma_f32_16x16x32_f16(A, B0, acc0, 0, 0, 0);
            acc1 = __builtin_amdgcn_mfma_f32_16x16x32_f16(A, B1, acc1, 0, 0, 0);

            #pragma unroll
            for (int r = 0; r < 4; ++r) {
                const int j = g * 4 + r;                 // C row j = edge t0+j
                if (t0 + j < end) {
                    const int srcr = __shfl(srcm, j);
                    const size_t sb = (size_t)srcr * 32;
                    const float ef0 = acc0[r] + be0;     // channel m (head 0)
                    const float ef1 = acc1[r] + be1;     // channel 16+m (head 1)
                    const float k0 = kb[sb + m], k1 = kb[sb + 16 + m];
                    const float v0 = vb[sb + m], v1 = vb[sb + 16 + m];

                    float p0 = q0 * (k0 + ef0);
                    float p1 = q1 * (k1 + ef1);
                    #pragma unroll
                    for (int s = 1; s < 16; s <<= 1) {
                        p0 += __shfl_xor(p0, s);
                        p1 += __shfl_xor(p1, s);
                    }
                    const float wg0 = __expf(p0 * INV_SQRT_C);
                    const float wg1 = __expf(p1 * INV_SQRT_C);
                    o0 = fmaf(wg0, v0 + ef0, o0);
                    o1 = fmaf(wg1, v1 + ef1, o1);
                    s0 += wg0; s1 += wg1;
                }
            }
        }

        // merge the 4 groups' partials
        o0 += __shfl_xor(o0, 16); o0 += __shfl_xor(o0, 32);
        o1 += __shfl_xor(o1, 16); o1 += __shfl_xor(o1, 32);
        s0 += __shfl_xor(s0, 16); s0 += __shfl_xor(s0, 32);
        s1 += __shfl_xor(s1, 16); s1 += __shfl_xor(s1, 32);

        const float h20 = o0 / (s0 + 1e-16f) + skipb[db + m];
        const float h21 = o1 / (s1 + 1e-16f) + skipb[db + 16 + m];

        float c0 = fmaf(h20, w00, h21 * w10);
        float c1 = fmaf(h20, w01, h21 * w11);
        #pragma unroll
        for (int s = 1; s < 16; s <<= 1) {
            c0 += __shfl_xor(c0, s);
            c1 += __shfl_xor(c1, s);
        }
        if (lane == 0) {
            const float oo0 = c0 + bo0, oo1 = c1 + bo1;
            const float mm = fmaxf(oo0, oo1);
            const float lse = mm + __logf(__expf(oo0 - mm) + __expf(oo1 - mm));
            out[(size_t)d * 2 + 0] = oo0 - lse;
            out[(size_t)d * 2 + 1] = oo1 - lse;
        }
    }
}

// ---------------------------------------------------------------------------
extern "C" void kernel_launch(void* const* d_in, const int* in_sizes, int n_in,
                              void* d_out, int out_size, void* d_ws, size_t ws_size,
                              hipStream_t stream)
{
    const float* x             = (const float*)d_in[0];
    const int*   ei            = (const int*)  d_in[1];
    const float* node_time     = (const float*)d_in[2];
    const float* edge_time     = (const float*)d_in[3];
    const float* node_interval = (const float*)d_in[4];
    const float* node_degree   = (const float*)d_in[5];
    const float* Wt    = (const float*)d_in[6];  const float* bt    = (const float*)d_in[7];
    const float* Wd    = (const float*)d_in[8];  const float* bd    = (const float*)d_in[9];
    const float* Wtf   = (const float*)d_in[10]; const float* btf   = (const float*)d_in[11];
    const float* Wenc  = (const float*)d_in[12]; const float* benc  = (const float*)d_in[13];
    const float* Wx    = (const float*)d_in[14]; const float* bx    = (const float*)d_in[15];
    const float* Wlin  = (const float*)d_in[16]; const float* blin  = (const float*)d_in[17];
    const float* Wcomb = (const float*)d_in[18]; const float* bcomb = (const float*)d_in[19];
    const float* Wq    = (const float*)d_in[20]; const float* bq    = (const float*)d_in[21];
    const float* Wk    = (const float*)d_in[22]; const float* bk    = (const float*)d_in[23];
    const float* Wv    = (const float*)d_in[24]; const float* bv    = (const float*)d_in[25];
    const float* We    = (const float*)d_in[26]; const float* be    = (const float*)d_in[27];
    const float* Wskip = (const float*)d_in[28]; const float* bskip = (const float*)d_in[29];
    const float* Wout  = (const float*)d_in[30]; const float* bout  = (const float*)d_in[31];

    const int n    = in_sizes[2];   // node_time: [N]
    const int numE = in_sizes[3];   // edge_time: [E,1]

    // ---- workspace carve (bytes) ----
    char* base = (char*)d_ws;
    float* qb    = (float*)base; base += (size_t)n * 32 * 4;
    float* kb    = (float*)base; base += (size_t)n * 32 * 4;
    float* vb    = (float*)base; base += (size_t)n * 32 * 4;
    float* skipb = (float*)base; base += (size_t)n * 32 * 4;
    // h1pre lives k1->k2 only; src_s (scatter->k3) reuses the same region.
    size_t reg5 = (size_t)n * 32 * 4;
    if ((size_t)numE * 4 > reg5) reg5 = (size_t)numE * 4;
    float* h1pre = (float*)base;
    int*   src_s = (int*)base;   base += reg5;
    _Float16* rel_h = (_Float16*)base; base += (((size_t)numE * 2) + 7) & ~(size_t)7;
    int* rowptr = (int*)base;    base += (size_t)(n + 1) * 4;
    int* cnt    = (int*)base;    base += (size_t)n * 4;       // counts, then cursor
    int* bsums  = (int*)base;    base += 1024 * 4;

    const int nb = (n + SCAN_ELEMS - 1) / SCAN_ELEMS;

    hipMemsetAsync(cnt, 0, (size_t)n * 4, stream);

    k1_lin<<<(n + 7) / 8, 256, 0, stream>>>(x, Wlin, blin, h1pre, n);

    k2_enc<<<(n + 255) / 256, 256, 0, stream>>>(
        h1pre, node_interval, node_degree,
        Wtf, btf, Wd, bd, Wenc, benc, Wx, bx, Wcomb, bcomb,
        Wq, bq, Wk, bk, Wv, bv, Wskip, bskip,
        qb, kb, vb, skipb, n);

    // counting sort by dst (after k2: src_s region aliases dead h1pre)
    k_hist<<<4096, 256, 0, stream>>>(ei, cnt, numE);
    k_scan1<<<nb, 256, 0, stream>>>(cnt, bsums, n);
    k_scan2<<<1, 1024, 0, stream>>>(bsums, nb);
    k_scan3<<<nb, 256, 0, stream>>>(cnt, bsums, rowptr, n, numE);
    k_scatter<<<4096, 256, 0, stream>>>(ei, node_time, edge_time, cnt,
                                        src_s, rel_h, numE);

    k3_fused<<<2048, 256, 0, stream>>>(
        rowptr, src_s, rel_h, qb, kb, vb, skipb,
        Wt, bt, We, be, Wout, bout, (float*)d_out, n);
}

// Round 6
// 508.766 us; speedup vs baseline: 1.4088x; 1.4088x over previous
//
#include <hip/hip_runtime.h>
#include <hip/hip_bf16.h>
#include <cstdint>

// TGAT fused pipeline for MI355X — round 6: edge-parallel MFMA attention with
// packed-bf16 atomics (no sort).
// Stages:
//   k1: h1pre = x @ Wlin + blin                        [N,32]
//   k2: node encoders + gated combine + Q/K/V/skip     [N,32] x4
//   k3: edge kernel — MFMA edge features + attention; accumulates
//       exp(alpha)*(v+e) via global_atomic_pk_add_bf16 (1 line/edge) and
//       exp(alpha) via 2 fp32 atomics (softmax normalization deferred;
//       shift-invariant, alpha is O(0.1))
//   k4: h2 = agg(bf16)/den + skip; out = log_softmax(h2 @ Wout + bout)
//
// Workspace: qb|kb|vb|skipb (4x12.8MB) | h1pre (12.8MB) | agg bf16 (6.4MB) |
//            den f32 (0.8MB)  ~= 71 MB

#define FIN 172
#define INV_SQRT_C 0.25f

typedef _Float16 f16x8 __attribute__((ext_vector_type(8)));
typedef float f32x4 __attribute__((ext_vector_type(4)));

// v_cvt_pk_bf16_f32: dst[15:0]=bf16(lo), dst[31:16]=bf16(hi), RNE. No builtin
// on gfx950 (m240) — inline asm.
__device__ __forceinline__ uint32_t cvt_pk_bf16(float lo, float hi) {
    uint32_t r;
    asm("v_cvt_pk_bf16_f32 %0, %1, %2" : "=v"(r) : "v"(lo), "v"(hi));
    return r;
}

// Fire-and-forget packed bf16 atomic add (2 channels / 4 bytes per op).
__device__ __forceinline__ void pk_atomic_add_bf16(void* addr, uint32_t data) {
    asm volatile("global_atomic_pk_add_bf16 %0, %1, off"
                 :: "v"((uint64_t)(uintptr_t)addr), "v"(data) : "memory");
}

// ---------------------------------------------------------------------------
// k1: h1pre = x @ Wlin + blin.  Block = 256 threads = 8 rows x 32 out-cols.
// ---------------------------------------------------------------------------
__global__ __launch_bounds__(256) void k1_lin(
    const float* __restrict__ x, const float* __restrict__ Wlin,
    const float* __restrict__ blin, float* __restrict__ h1pre, int n)
{
    __shared__ __align__(16) float WlT[32][174];   // [out][k], padded
    __shared__ __align__(16) float xs[8][FIN];
    const int t = threadIdx.x;

    for (int i = t; i < FIN * 32; i += 256) {
        int kk = i >> 5, o = i & 31;               // Wlin row-major [k][o]
        WlT[o][kk] = Wlin[i];
    }
    const int row0 = blockIdx.x * 8;
    for (int i = t; i < 8 * FIN; i += 256) {
        int rr = i / FIN, kk = i - rr * FIN;
        int gr = row0 + rr;
        xs[rr][kk] = (gr < n) ? x[(size_t)gr * FIN + kk] : 0.f;
    }
    __syncthreads();

    const int o = t & 31, r = t >> 5;
    float acc = blin[o];
    const float2* wp = reinterpret_cast<const float2*>(&WlT[o][0]);
    const float2* xp = reinterpret_cast<const float2*>(&xs[r][0]);
    #pragma unroll 4
    for (int kk = 0; kk < FIN / 2; ++kk) {
        float2 wv = wp[kk], xv = xp[kk];
        acc = fmaf(xv.x, wv.x, acc);
        acc = fmaf(xv.y, wv.y, acc);
    }
    const int gr = row0 + r;
    if (gr < n) h1pre[(size_t)gr * 32 + o] = acc;
}

// ---------------------------------------------------------------------------
// Small matvec helper: out[o] = B[o] + sum_k v[k] * W[k*O + o]. W/B in LDS.
// ---------------------------------------------------------------------------
template <int K, int O>
__device__ __forceinline__ void matvecKO(const float* __restrict__ v,
                                         const float* __restrict__ W,
                                         const float* __restrict__ B,
                                         float* __restrict__ out)
{
    #pragma unroll
    for (int o4 = 0; o4 < O / 4; ++o4) {
        float a0 = B[o4 * 4 + 0], a1 = B[o4 * 4 + 1];
        float a2 = B[o4 * 4 + 2], a3 = B[o4 * 4 + 3];
        #pragma unroll
        for (int k = 0; k < K; ++k) {
            float4 wv = *reinterpret_cast<const float4*>(&W[k * O + o4 * 4]);
            float hv = v[k];
            a0 = fmaf(hv, wv.x, a0);
            a1 = fmaf(hv, wv.y, a1);
            a2 = fmaf(hv, wv.z, a2);
            a3 = fmaf(hv, wv.w, a3);
        }
        out[o4 * 4 + 0] = a0; out[o4 * 4 + 1] = a1;
        out[o4 * 4 + 2] = a2; out[o4 * 4 + 3] = a3;
    }
}

__device__ __forceinline__ void store32(float* __restrict__ dst,
                                        const float* __restrict__ v)
{
    float4* d4 = reinterpret_cast<float4*>(dst);
    #pragma unroll
    for (int i = 0; i < 8; ++i)
        d4[i] = make_float4(v[4 * i], v[4 * i + 1], v[4 * i + 2], v[4 * i + 3]);
}

// ---------------------------------------------------------------------------
// k2: per-node encoder + combine + projections. One thread per node.
// ---------------------------------------------------------------------------
__global__ __launch_bounds__(256) void k2_enc(
    const float* __restrict__ h1pre,
    const float* __restrict__ node_interval, const float* __restrict__ node_degree,
    const float* __restrict__ Wtf, const float* __restrict__ btf,
    const float* __restrict__ Wd,  const float* __restrict__ bd,
    const float* __restrict__ Wenc, const float* __restrict__ benc,
    const float* __restrict__ Wx,  const float* __restrict__ bx,
    const float* __restrict__ Wcomb, const float* __restrict__ bcomb,
    const float* __restrict__ Wq,  const float* __restrict__ bq,
    const float* __restrict__ Wk,  const float* __restrict__ bk,
    const float* __restrict__ Wv,  const float* __restrict__ bv,
    const float* __restrict__ Wskip, const float* __restrict__ bskip,
    float* __restrict__ qb, float* __restrict__ kb, float* __restrict__ vb,
    float* __restrict__ skipb, int n)
{
    __shared__ __align__(16) float sWenc[64], sWx[256], sWcomb[1280];
    __shared__ __align__(16) float sWq[1024], sWk[1024], sWv[1024], sWs[1024];
    __shared__ float sWtf[8], sbtf[8], sWd[8], sbd[8], sbenc[8], sbx[8];
    __shared__ float sbcomb[32], sbq[32], sbk[32], sbv[32], sbs[32];

    const int t = threadIdx.x;
    if (t < 8) {
        sWtf[t] = Wtf[t]; sbtf[t] = btf[t];
        sWd[t]  = Wd[t];  sbd[t]  = bd[t];
        sbenc[t] = benc[t]; sbx[t] = bx[t];
    }
    if (t < 32) {
        sbcomb[t] = bcomb[t]; sbq[t] = bq[t]; sbk[t] = bk[t];
        sbv[t] = bv[t]; sbs[t] = bskip[t];
    }
    if (t < 64) sWenc[t] = Wenc[t];
    if (t < 256) sWx[t] = Wx[t];
    for (int i = t; i < 1280; i += 256) sWcomb[i] = Wcomb[i];
    for (int i = t; i < 1024; i += 256) {
        sWq[i] = Wq[i]; sWk[i] = Wk[i]; sWv[i] = Wv[i]; sWs[i] = Wskip[i];
    }
    __syncthreads();

    const int nid = blockIdx.x * 256 + t;
    if (nid >= n) return;

    float h1p[32];
    {
        const float2* hp = reinterpret_cast<const float2*>(h1pre + (size_t)nid * 32);
        #pragma unroll
        for (int i = 0; i < 16; ++i) {
            float2 v2 = hp[i];
            h1p[2 * i] = v2.x; h1p[2 * i + 1] = v2.y;
        }
    }
    const float ti = node_interval[nid], dg = node_degree[nid];
    float tf[8], de[8];
    #pragma unroll
    for (int j = 0; j < 8; ++j) {
        tf[j] = fmaf(ti, sWtf[j], sbtf[j]);
        de[j] = fmaf(dg, sWd[j], sbd[j]);
    }
    float xp[8];
    matvecKO<32, 8>(h1p, sWx, sbx, xp);
    #pragma unroll
    for (int o = 0; o < 8; ++o) xp[o] = tanhf(xp[o]);

    float ep0[8], ep1[8];
    matvecKO<8, 8>(tf, sWenc, sbenc, ep0);
    matvecKO<8, 8>(de, sWenc, sbenc, ep1);
    float sc0 = 0.f, sc1 = 0.f;
    #pragma unroll
    for (int o = 0; o < 8; ++o) {
        sc0 = fmaf(tanhf(ep0[o]), xp[o], sc0);
        sc1 = fmaf(tanhf(ep1[o]), xp[o], sc1);
    }
    const float mm = fmaxf(sc0, sc1);
    const float e0 = __expf(sc0 - mm), e1 = __expf(sc1 - mm);
    const float inv = 1.f / (e0 + e1);
    const float s0 = e0 * inv, s1 = e1 * inv;

    float v40[40];
    #pragma unroll
    for (int i = 0; i < 32; ++i) v40[i] = h1p[i];
    #pragma unroll
    for (int j = 0; j < 8; ++j) v40[32 + j] = fmaf(s0, tf[j], s1 * de[j]);
    float h1[32];
    matvecKO<40, 32>(v40, sWcomb, sbcomb, h1);

    float tmp[32];
    matvecKO<32, 32>(h1, sWq, sbq, tmp); store32(qb   + (size_t)nid * 32, tmp);
    matvecKO<32, 32>(h1, sWk, sbk, tmp); store32(kb   + (size_t)nid * 32, tmp);
    matvecKO<32, 32>(h1, sWv, sbv, tmp); store32(vb   + (size_t)nid * 32, tmp);
    matvecKO<32, 32>(h1, sWs, sbs, tmp); store32(skipb + (size_t)nid * 32, tmp);
}

// ---------------------------------------------------------------------------
// k3: edge kernel. One wave = one 16-edge tile (grid-stride persistent).
// Two mfma_f32_16x16x32_f16 compute the 16x32 edge-feature tile
// (A row = lane&15, k = 8*(lane>>4)+i; B col = lane&15, same k map;
// C col = lane&15, row = 4*(lane>>4)+reg — m89-verified; in-group k-order
// discrepancies cancel since A and B share the map and sum_k commutes).
//
// Output: per edge, 16 packed-bf16 atomics (channel pairs built by
// shfl_xor(1) + v_cvt_pk_bf16_f32; one 64B line per edge) + 2 fp32 den
// atomics. 18 ops / 72 B per edge vs round-3's 34 ops / 136 B.
// ---------------------------------------------------------------------------
__global__ __launch_bounds__(256) void k3_edge(
    const int* __restrict__ ei, const float* __restrict__ node_time,
    const float* __restrict__ edge_time,
    const float* __restrict__ qb, const float* __restrict__ kb,
    const float* __restrict__ vb,
    const float* __restrict__ Wt, const float* __restrict__ bt,
    const float* __restrict__ We, const float* __restrict__ be,
    unsigned short* __restrict__ agg, float* __restrict__ den,
    int numE, int nTiles)
{
    const int lane = threadIdx.x & 63;
    const int g = lane >> 4;          // k-group / C row group
    const int m = lane & 15;          // A row (edge-in-tile) / B,C column

    // Per-thread constants (amortized over the grid-stride loop).
    float wtr[8], btr[8];
    f16x8 B0, B1;
    #pragma unroll
    for (int i = 0; i < 8; ++i) {
        const int k = g * 8 + i;
        wtr[i] = Wt[k];
        btr[i] = bt[k];
        B0[i] = (_Float16)We[k * 32 + m];
        B1[i] = (_Float16)We[k * 32 + 16 + m];
    }
    const float be0 = be[m], be1 = be[16 + m];

    const int wid    = blockIdx.x * (blockDim.x >> 6) + (threadIdx.x >> 6);
    const int nWaves = gridDim.x * (blockDim.x >> 6);

    for (int tile = wid; tile < nTiles; tile += nWaves) {
        const int e0 = tile * 16;
        const int eA = e0 + m;                     // edge whose metadata this lane owns
        int srcm = 0, dstm = 0;
        float rel = 0.f;
        if (eA < numE) {
            srcm = ei[eA];
            dstm = ei[numE + eA];
            rel  = node_time[srcm] - edge_time[eA];
        }

        // A fragment: ct[k] for edge row m, k = 8g+i.
        f16x8 A;
        #pragma unroll
        for (int i = 0; i < 8; ++i)
            A[i] = (_Float16)__cosf(fmaf(rel, wtr[i], btr[i]));

        f32x4 acc0 = {0.f, 0.f, 0.f, 0.f};
        f32x4 acc1 = {0.f, 0.f, 0.f, 0.f};
        acc0 = __builtin_amdgcn_mfma_f32_16x16x32_f16(A, B0, acc0, 0, 0, 0);
        acc1 = __builtin_amdgcn_mfma_f32_16x16x32_f16(A, B1, acc1, 0, 0, 0);

        #pragma unroll
        for (int r = 0; r < 4; ++r) {
            const int j = g * 4 + r;               // edge-in-tile this reg row holds
            const int e = e0 + j;
            if (e < numE) {
                const int srcr = __shfl(srcm, j);  // lane j owns edge e0+j's metadata
                const int dstr = __shfl(dstm, j);

                const float ef0 = acc0[r] + be0;   // channel m      (head 0)
                const float ef1 = acc1[r] + be1;   // channel 16+m   (head 1)

                const size_t sb = (size_t)srcr * 32;
                const size_t db = (size_t)dstr * 32;
                const float q0 = qb[db + m],      q1 = qb[db + 16 + m];
                const float k0 = kb[sb + m],      k1 = kb[sb + 16 + m];
                const float v0 = vb[sb + m],      v1 = vb[sb + 16 + m];

                float p0 = q0 * (k0 + ef0);
                float p1 = q1 * (k1 + ef1);
                #pragma unroll
                for (int s = 1; s < 16; s <<= 1) { // reduce over the 16 channels
                    p0 += __shfl_xor(p0, s);
                    p1 += __shfl_xor(p1, s);
                }
                const float w0 = __expf(p0 * INV_SQRT_C);
                const float w1 = __expf(p1 * INV_SQRT_C);

                const float t0 = w0 * (v0 + ef0);  // contribution to ch m
                const float t1 = w1 * (v1 + ef1);  // contribution to ch 16+m
                const float x0 = __shfl_xor(t0, 1);
                const float x1 = __shfl_xor(t1, 1);
                // even lane m: pair (m, m+1) from head-0 values
                // odd  lane m: pair (15+m, 16+m) from head-1 values
                const uint32_t dE = cvt_pk_bf16(t0, x0);
                const uint32_t dO = cvt_pk_bf16(x1, t1);
                const uint32_t data = (m & 1) ? dO : dE;
                const int choff = (m & 1) ? (15 + m) : m;
                pk_atomic_add_bf16(agg + db + choff, data);

                if (m < 2) atomicAdd(&den[(size_t)dstr * 2 + m], m ? w1 : w0);
            }
        }
    }
}

// ---------------------------------------------------------------------------
// k4: h2 = agg(bf16)/den + skip; out = log_softmax(h2 @ Wout + bout).
// ---------------------------------------------------------------------------
__global__ __launch_bounds__(256) void k4_out(
    const unsigned short* __restrict__ agg, const float* __restrict__ den,
    const float* __restrict__ skipb,
    const float* __restrict__ Wout, const float* __restrict__ bout,
    float* __restrict__ out, int n)
{
    __shared__ float sW[64];
    __shared__ float sb[2];
    const int t = threadIdx.x;
    if (t < 64) sW[t] = Wout[t];
    if (t < 2) sb[t] = bout[t];
    __syncthreads();

    const int nid = blockIdx.x * 256 + t;
    if (nid >= n) return;

    const float inv0 = 1.f / (den[(size_t)nid * 2 + 0] + 1e-16f);
    const float inv1 = 1.f / (den[(size_t)nid * 2 + 1] + 1e-16f);
    const uint32_t* ag = reinterpret_cast<const uint32_t*>(agg) + (size_t)nid * 16;
    const float4*  sk4 = reinterpret_cast<const float4*>(skipb + (size_t)nid * 32);

    float o0 = sb[0], o1 = sb[1];
    #pragma unroll
    for (int p = 0; p < 16; ++p) {                 // channel pair (2p, 2p+1)
        const uint32_t u = ag[p];
        const float aLo = __uint_as_float(u << 16);
        const float aHi = __uint_as_float(u & 0xFFFF0000u);
        const float iv = (p < 8) ? inv0 : inv1;
        const float s0 = reinterpret_cast<const float*>(sk4)[2 * p];
        const float s1 = reinterpret_cast<const float*>(sk4)[2 * p + 1];
        const float hLo = fmaf(aLo, iv, s0);
        const float hHi = fmaf(aHi, iv, s1);
        o0 = fmaf(hLo, sW[(2 * p) * 2],     o0);
        o1 = fmaf(hLo, sW[(2 * p) * 2 + 1], o1);
        o0 = fmaf(hHi, sW[(2 * p + 1) * 2],     o0);
        o1 = fmaf(hHi, sW[(2 * p + 1) * 2 + 1], o1);
    }
    const float mm = fmaxf(o0, o1);
    const float lse = mm + __logf(__expf(o0 - mm) + __expf(o1 - mm));
    out[(size_t)nid * 2 + 0] = o0 - lse;
    out[(size_t)nid * 2 + 1] = o1 - lse;
}

// ---------------------------------------------------------------------------
extern "C" void kernel_launch(void* const* d_in, const int* in_sizes, int n_in,
                              void* d_out, int out_size, void* d_ws, size_t ws_size,
                              hipStream_t stream)
{
    const float* x             = (const float*)d_in[0];
    const int*   ei            = (const int*)  d_in[1];
    const float* node_time     = (const float*)d_in[2];
    const float* edge_time     = (const float*)d_in[3];
    const float* node_interval = (const float*)d_in[4];
    const float* node_degree   = (const float*)d_in[5];
    const float* Wt    = (const float*)d_in[6];  const float* bt    = (const float*)d_in[7];
    const float* Wd    = (const float*)d_in[8];  const float* bd    = (const float*)d_in[9];
    const float* Wtf   = (const float*)d_in[10]; const float* btf   = (const float*)d_in[11];
    const float* Wenc  = (const float*)d_in[12]; const float* benc  = (const float*)d_in[13];
    const float* Wx    = (const float*)d_in[14]; const float* bx    = (const float*)d_in[15];
    const float* Wlin  = (const float*)d_in[16]; const float* blin  = (const float*)d_in[17];
    const float* Wcomb = (const float*)d_in[18]; const float* bcomb = (const float*)d_in[19];
    const float* Wq    = (const float*)d_in[20]; const float* bq    = (const float*)d_in[21];
    const float* Wk    = (const float*)d_in[22]; const float* bk    = (const float*)d_in[23];
    const float* Wv    = (const float*)d_in[24]; const float* bv    = (const float*)d_in[25];
    const float* We    = (const float*)d_in[26]; const float* be    = (const float*)d_in[27];
    const float* Wskip = (const float*)d_in[28]; const float* bskip = (const float*)d_in[29];
    const float* Wout  = (const float*)d_in[30]; const float* bout  = (const float*)d_in[31];

    const int n    = in_sizes[2];   // node_time: [N]
    const int numE = in_sizes[3];   // edge_time: [E,1]

    // ---- workspace carve (bytes) ----
    char* base = (char*)d_ws;
    float* qb    = (float*)base; base += (size_t)n * 32 * 4;
    float* kb    = (float*)base; base += (size_t)n * 32 * 4;
    float* vb    = (float*)base; base += (size_t)n * 32 * 4;
    float* skipb = (float*)base; base += (size_t)n * 32 * 4;
    float* h1pre = (float*)base; base += (size_t)n * 32 * 4;
    unsigned short* agg = (unsigned short*)base; base += (size_t)n * 32 * 2;
    float* den   = (float*)base; base += (size_t)n * 2 * 4;

    // zero the atomic accumulators (agg bf16 + den f32, contiguous)
    hipMemsetAsync(agg, 0, (size_t)n * (32 * 2 + 2 * 4), stream);

    k1_lin<<<(n + 7) / 8, 256, 0, stream>>>(x, Wlin, blin, h1pre, n);

    k2_enc<<<(n + 255) / 256, 256, 0, stream>>>(
        h1pre, node_interval, node_degree,
        Wtf, btf, Wd, bd, Wenc, benc, Wx, bx, Wcomb, bcomb,
        Wq, bq, Wk, bk, Wv, bv, Wskip, bskip,
        qb, kb, vb, skipb, n);

    const int nTiles = (numE + 15) / 16;
    k3_edge<<<2048, 256, 0, stream>>>(
        ei, node_time, edge_time, qb, kb, vb,
        Wt, bt, We, be, agg, den, numE, nTiles);

    k4_out<<<(n + 255) / 256, 256, 0, stream>>>(
        agg, den, skipb, Wout, bout, (float*)d_out, n);
}